// Round 7
// baseline (1510.363 us; speedup 1.0000x reference)
//
#include <hip/hip_runtime.h>
#include <stdint.h>

// Problem constants
#define NBATCH 16
#define NNODE  20
#define TSTEPS 63      // T-1
#define NEDGE  380
#define HID    256
#define RS     280     // hst row stride in shorts (16B-aligned rows, phase-clean b128)

typedef __bf16 bf16x8 __attribute__((ext_vector_type(8)));
typedef float  f32x4  __attribute__((ext_vector_type(4)));

__device__ __forceinline__ float bf2f(unsigned short u){
  union { unsigned int i; float f; } v; v.i = ((unsigned int)u) << 16; return v.f;
}
__device__ __forceinline__ unsigned short f2bf(float f){
  union { float f; unsigned int i; } v; v.f = f;
  return (unsigned short)((v.i + 0x7FFFu + ((v.i >> 16) & 1u)) >> 16);
}
__device__ __forceinline__ bf16x8 as_frag(uint4 v){
  union { uint4 u; bf16x8 b; } c; c.u = v; return c.b;
}
__device__ __forceinline__ float sigmf(float x){ return 1.0f/(1.0f+__expf(-x)); }
__device__ __forceinline__ float tanh_f(float x){ float e=__expf(2.0f*x); return (e-1.0f)/(e+1.0f); }

// Relaxed agent-scope ops: per-access sc1 (LLC = coherence point), no cache-wide inv/wb.
__device__ __forceinline__ unsigned long long load_ax(const unsigned long long* p){
  return __hip_atomic_load(p, __ATOMIC_RELAXED, __HIP_MEMORY_SCOPE_AGENT);
}
__device__ __forceinline__ void store_ax(unsigned long long* p, unsigned long long v){
  __hip_atomic_store(p, v, __ATOMIC_RELAXED, __HIP_MEMORY_SCOPE_AGENT);
}
__device__ __forceinline__ void wait_vm0(){ asm volatile("s_waitcnt vmcnt(0)" ::: "memory"); }

// In-register 4x4 gate transpose among lanes cl^1, cl^2 (gate-interleaved cols). [proven R4-R6]
__device__ __forceinline__ void xpose4(f32x4& v, int cl){
  float s0 = __shfl_xor((float)v[1], 1), s1 = __shfl_xor((float)v[0], 1);
  float s2 = __shfl_xor((float)v[3], 1), s3 = __shfl_xor((float)v[2], 1);
  bool b0 = (cl & 1);
  float a0 = b0 ? s0 : v[0], a1 = b0 ? v[1] : s1;
  float a2 = b0 ? s2 : v[2], a3 = b0 ? v[3] : s3;
  float t0 = __shfl_xor(a2, 2), t1 = __shfl_xor(a3, 2);
  float t2 = __shfl_xor(a0, 2), t3 = __shfl_xor(a1, 2);
  bool b1 = (cl & 2);
  v[0] = b1 ? t0 : a0; v[1] = b1 ? t1 : a1;
  v[2] = b1 ? a2 : t2; v[3] = b1 ? a3 : t3;
}

// ---------------------------------------------------------------------------
// prep_a: combined weights (fp32) + interleaved biases + zero counters/Afin.
__global__ __launch_bounds__(256) void prep_a(
    const float* __restrict__ We, const float* __restrict__ Wei,
    const float* __restrict__ Wm, const float* __restrict__ Wmi,
    const float* __restrict__ bm, const float* __restrict__ bmi, const float* __restrict__ bmh,
    const float* __restrict__ be, const float* __restrict__ bei, const float* __restrict__ beh,
    float* __restrict__ Wse, float* __restrict__ Wre, float* __restrict__ WcmGI,
    float* __restrict__ bcmGI, float* __restrict__ bceGI,
    float* __restrict__ Afin, unsigned int* __restrict__ ectr, unsigned int* __restrict__ mctr){
  int bid = blockIdx.x, tid = threadIdx.x;
  if (bid < 2048){
    int idx = bid*256 + tid;
    int half = idx >> 18;
    int j = idx & 262143;
    int k = j >> 10, nn = j & 1023;
    const float* Wrow = We + (half*256 + k)*128;
    float s = 0.f;
    for (int d = 0; d < 128; ++d) s += Wrow[d] * Wei[d*1024 + nn];
    (half ? Wre : Wse)[k*1024 + nn] = s;
  } else if (bid < 2064){
    int idx = (bid-2048)*256 + tid;
    int d = idx >> 10, ci = idx & 1023;
    int col = (ci & 3)*256 + (ci >> 2);
    float s = 0.f;
    for (int j = 0; j < 128; ++j) s += Wm[d*128 + j] * Wmi[j*1024 + col];
    WcmGI[idx] = s;
  } else if (bid < 2068){
    int ci = (bid-2064)*256 + tid;
    int col = (ci & 3)*256 + (ci >> 2);
    float s = bmi[col] + bmh[col];
    for (int j = 0; j < 128; ++j) s += bm[j] * Wmi[j*1024 + col];
    bcmGI[ci] = s;
  } else if (bid < 2072){
    int ci = (bid-2068)*256 + tid;
    int col = (ci & 3)*256 + (ci >> 2);
    float s = bei[col] + beh[col];
    for (int j = 0; j < 128; ++j) s += be[j] * Wei[j*1024 + col];
    bceGI[ci] = s;
  } else if (bid == 2072){
    for (int i = tid; i < 4096; i += 256) ectr[i] = 0u;   // 128 groups x 128 B pad
    for (int i = tid; i < 1024; i += 256) mctr[i] = 0u;   // 32 groups x 128 B pad
  } else {
    int idx = (bid-2073)*256 + tid;
    if (idx < NBATCH*NEDGE) Afin[idx] = 0.f;
  }
}

// ---------------------------------------------------------------------------
// prep_b packing (verified R2-R6).
__device__ __forceinline__ void pack_gi(const float* __restrict__ W,
                                        unsigned short* __restrict__ dst, int id){
  int lane = id & 63, kt = (id >> 6) & 7, tt = (id >> 9) & 1, w = (id >> 10) & 7, nb = id >> 13;
  int cl = lane & 15, q = lane >> 4;
  int gcol = (cl & 3)*256 + nb*64 + (w*2 + tt)*4 + (cl >> 2);
  int k0 = kt*32 + q*8;
  unsigned int wb[4];
  #pragma unroll
  for (int p = 0; p < 4; ++p){
    unsigned short a = f2bf(W[(k0+2*p  )*1024 + gcol]);
    unsigned short b = f2bf(W[(k0+2*p+1)*1024 + gcol]);
    wb[p] = (unsigned int)a | ((unsigned int)b << 16);
  }
  ((uint4*)dst)[id] = make_uint4(wb[0], wb[1], wb[2], wb[3]);
}

__device__ __forceinline__ void pack_one(const float* __restrict__ S,
                                         unsigned short* __restrict__ dst, int id, int n){
  int lane = id & 63, kt = (id >> 6) & 7;
  int k0 = kt*32 + ((lane >> 4) << 3);
  unsigned int wb[4];
  #pragma unroll
  for (int p = 0; p < 4; ++p){
    unsigned short a = f2bf(S[(k0+2*p  )*1024 + n]);
    unsigned short b = f2bf(S[(k0+2*p+1)*1024 + n]);
    wb[p] = (unsigned int)a | ((unsigned int)b << 16);
  }
  ((uint4*)dst)[id] = make_uint4(wb[0], wb[1], wb[2], wb[3]);
}

__global__ __launch_bounds__(256) void prep_b(
    const float* __restrict__ Wmh, const float* __restrict__ Weh,
    const float* __restrict__ Wse, const float* __restrict__ Wre,
    unsigned short* __restrict__ pWmh, unsigned short* __restrict__ pWeh,
    unsigned short* __restrict__ pWsr){
  int gid = blockIdx.x*256 + threadIdx.x;
  if (gid < 32768){
    pack_gi(Wmh, pWmh, gid);
  } else if (gid < 65536){
    pack_gi(Weh, pWeh, gid - 32768);
  } else {
    int id = gid - 65536;
    int ng = (id >> 9)*16 + (id & 15);
    const float* S = (ng < 1024) ? Wse : Wre;
    pack_one(S, pWsr, id, ng & 1023);
  }
}

// ---------------------------------------------------------------------------
// motion_lstm: grid 128 = 32 m (10 seqs) x 4 n. 512 thr = 8 waves. (R6, unchanged)
__global__ __launch_bounds__(512, 2) void motion_lstm(
    const float* __restrict__ X, const float* __restrict__ WcmGI,
    const float* __restrict__ bcmGI, const unsigned short* __restrict__ pWmh,
    unsigned short* __restrict__ hm, unsigned short* __restrict__ mb,
    unsigned int* __restrict__ mctr){
  __shared__ __align__(16) unsigned short hst[16*RS];
  __shared__ float dxs[10*252];
  __shared__ __align__(16) float sWc[4*256];
  __shared__ __align__(16) float sbc[256];
  int tid = threadIdx.x, lane = tid & 63, w = tid >> 6;
  int l15 = lane & 15, quad = lane >> 4;
  int m = blockIdx.x & 31, n = blockIdx.x >> 5;
  int s0 = m*10;
  unsigned int* ctr = mctr + m*32;

  uint4 wreg[2][8];
  #pragma unroll
  for (int tt = 0; tt < 2; ++tt)
    #pragma unroll
    for (int kt = 0; kt < 8; ++kt)
      wreg[tt][kt] = ((const uint4*)pWmh)[(((n*8 + w)*2 + tt)*8 + kt)*64 + lane];

  uint4 z4 = make_uint4(0,0,0,0);
  for (int i = tid; i < 560; i += 512) ((uint4*)hst)[i] = z4;
  for (int i = tid; i < 1024; i += 512) sWc[i] = WcmGI[(i >> 8)*1024 + n*256 + (i & 255)];
  if (tid < 256) sbc[tid] = bcmGI[n*256 + tid];
  for (int i = tid; i < 2520; i += 512){
    int sl = i / 252; int r = i % 252; int t = r >> 2; int d = r & 3;
    const float* Xp = X + (((size_t)(s0 + sl)*64 + t)*4 + d);
    dxs[i] = Xp[4] - Xp[0];
  }
  __syncthreads();

  float bb[2] = { sbc[(w*2+0)*16 + l15], sbc[(w*2+1)*16 + l15] };
  int row = quad*4 + (l15 & 3);
  int hsub = l15 >> 2;
  int slr = row < 10 ? row : 9;
  float ce[2] = {0.f, 0.f};

  for (int t = 0; t < TSTEPS; ++t){
    if (t > 0){
      if (tid == 0){
        unsigned int tgt = 4u*(unsigned)t;
        while (__hip_atomic_load(ctr, __ATOMIC_RELAXED, __HIP_MEMORY_SCOPE_AGENT) < tgt)
          __builtin_amdgcn_s_sleep(1);
      }
      __syncthreads();                                    // B1
      const unsigned long long* mbp = (const unsigned long long*)mb
          + ((size_t)((t-1)&1)*32 + m)*16*64;
      unsigned long long pv[2]; int po[2] = {-1,-1};
      #pragma unroll
      for (int j = 0; j < 2; ++j){
        int i = tid + j*512;
        if (i < 768){
          int which = i >> 8, jj = i & 255;
          int r = jj >> 4, c = jj & 15;
          int np = which + (which >= n ? 1 : 0);
          pv[j] = load_ax(&mbp[(size_t)r*64 + np*16 + c]);
          po[j] = r*RS + np*64 + c*4;
        }
      }
      #pragma unroll
      for (int j = 0; j < 2; ++j)
        if (po[j] >= 0) *(unsigned long long*)&hst[po[j]] = pv[j];
    }
    __syncthreads();                                      // B2

    f32x4 acc[2];
    acc[0] = (f32x4){bb[0],bb[0],bb[0],bb[0]};
    acc[1] = (f32x4){bb[1],bb[1],bb[1],bb[1]};
    #pragma unroll
    for (int kt = 0; kt < 8; ++kt){
      bf16x8 a = as_frag(*(const uint4*)&hst[l15*RS + kt*32 + quad*8]);
      acc[0] = __builtin_amdgcn_mfma_f32_16x16x32_bf16(a, as_frag(wreg[0][kt]), acc[0], 0, 0, 0);
      acc[1] = __builtin_amdgcn_mfma_f32_16x16x32_bf16(a, as_frag(wreg[1][kt]), acc[1], 0, 0, 0);
    }
    __syncthreads();                                      // B3

    f32x4 dxv = *(const f32x4*)&dxs[slr*252 + t*4];
    #pragma unroll
    for (int tt = 0; tt < 2; ++tt){
      int tl = w*2 + tt;
      f32x4 v = acc[tt];
      xpose4(v, l15);
      #pragma unroll
      for (int d = 0; d < 4; ++d){
        f32x4 wv = *(const f32x4*)&sWc[d*256 + tl*16 + hsub*4];
        v[0] += dxv[d]*wv[0]; v[1] += dxv[d]*wv[1];
        v[2] += dxv[d]*wv[2]; v[3] += dxv[d]*wv[3];
      }
      float iv = sigmf(v[0]), fv = sigmf(v[1]), gg = tanh_f(v[2]), ov = sigmf(v[3]);
      float cc = fv*ce[tt] + iv*gg; ce[tt] = cc;
      hst[row*RS + n*64 + tl*4 + hsub] = f2bf(ov*tanh_f(cc));
    }
    __syncthreads();                                      // B4

    unsigned long long* mbc = (unsigned long long*)mb
        + ((size_t)(t&1)*32 + m)*16*64;
    if (tid < 256){
      int r = tid >> 4, c = tid & 15;
      unsigned long long v = *(const unsigned long long*)&hst[r*RS + n*64 + c*4];
      if (t < 62) store_ax(&mbc[(size_t)r*64 + n*16 + c], v);
      if (r < 10){
        int seq = s0 + r;
        int b2 = seq / 20, nd = seq - (seq/20)*20;
        *(unsigned long long*)&hm[(((size_t)(b2*63 + t)*20) + nd)*256 + n*64 + c*4] = v;
      }
    }
    wait_vm0();
    __syncthreads();                                      // B5
    if (t < 62 && tid == 0)
      __hip_atomic_fetch_add(ctr, 1u, __ATOMIC_RELAXED, __HIP_MEMORY_SCOPE_AGENT);
  }
}

// ---------------------------------------------------------------------------
// gsr_gemm: hm2 (t-major) @ [Wse|Wre] -> gsrT records, coalesced aligned writes.
// Record (48 shorts, 96 B) per (bt = b*63+t, ch = gate*256+hcol):
//   shorts 0..19  = receiver proj (Wre) nodes 0..19, 20..23 pad
//   shorts 24..43 = sender proj (Wse) nodes 0..19, 44..47 pad
__global__ __launch_bounds__(256) void gsr_gemm(
    const unsigned short* __restrict__ hm, const unsigned short* __restrict__ pWsr,
    unsigned short* __restrict__ gsrT){
  __shared__ __align__(16) unsigned short scol[128*100];   // [col][row], stride 100
  int tid = threadIdx.x, lane = tid & 63, wid = tid >> 6;
  int l15 = lane & 15, quad = lane >> 4;
  int bm = blockIdx.x % 252, bn = blockIdx.x / 252;
  int rowbase = bm*80;
  f32x4 acc[5][2] = {};
  #pragma unroll
  for (int kt = 0; kt < 8; ++kt){
    bf16x8 af[5];
    #pragma unroll
    for (int mt = 0; mt < 5; ++mt)
      af[mt] = as_frag(*(const uint4*)&hm[(size_t)(rowbase + mt*16 + l15)*256 + kt*32 + quad*8]);
    #pragma unroll
    for (int j = 0; j < 2; ++j){
      int ntg = bn*8 + wid*2 + j;
      bf16x8 bfr = as_frag(*(const uint4*)&pWsr[(((size_t)ntg*8 + kt)*64 + lane)*8]);
      #pragma unroll
      for (int mt = 0; mt < 5; ++mt)
        acc[mt][j] = __builtin_amdgcn_mfma_f32_16x16x32_bf16(af[mt], bfr, acc[mt][j], 0, 0, 0);
    }
  }
  #pragma unroll
  for (int mt = 0; mt < 5; ++mt)
    #pragma unroll
    for (int j = 0; j < 2; ++j){
      int colL = (wid*2 + j)*16 + l15;
      unsigned int p0 = (unsigned)f2bf(acc[mt][j][0]) | ((unsigned)f2bf(acc[mt][j][1]) << 16);
      unsigned int p1 = (unsigned)f2bf(acc[mt][j][2]) | ((unsigned)f2bf(acc[mt][j][3]) << 16);
      *(uint2*)&scol[colL*100 + mt*16 + quad*4] = make_uint2(p0, p1);
    }
  __syncthreads();
  int recv = bn >> 3;   // 0 = Wse (sender cols), 1 = Wre (receiver cols)
  int doff = recv ? 0 : 24;
  #pragma unroll
  for (int rep = 0; rep < 2; ++rep){
    int i = tid + rep*256;
    int btl = i >> 7, colL = i & 127;
    const unsigned short* sp = &scol[colL*100 + btl*20];
    uint2 u0 = *(const uint2*)(sp);
    uint2 u1 = *(const uint2*)(sp+4);
    uint2 u2 = *(const uint2*)(sp+8);
    uint2 u3 = *(const uint2*)(sp+12);
    uint2 u4 = *(const uint2*)(sp+16);
    unsigned short* dp = gsrT + ((size_t)(bm*4 + btl)*1024 + (bn&7)*128 + colL)*48 + doff;
    *(uint4*)(dp)      = make_uint4(u0.x, u0.y, u1.x, u1.y);
    *(uint4*)(dp + 8)  = make_uint4(u2.x, u2.y, u3.x, u3.y);
    *(uint2*)(dp + 16) = u4;
  }
}

// ---------------------------------------------------------------------------
// edge_lstm: grid 512 = 16 b x 8 m (48 edges) x 4 n. 512 thr = 8 waves.
// LDS 69 KB -> 2 blocks/CU (latency hiding). One-hot xg K-tile: k<20 recv node k,
// k=24+i -> sender node smin+i (span <= 4). R6 sync skeleton.
__device__ __forceinline__ void stage_gxb(const unsigned short* __restrict__ gsrT,
                                          unsigned short* __restrict__ gx,
                                          int tid, int b, int smin, int n, int tq){
  const unsigned short* base = gsrT + (size_t)(b*63 + tq)*1024*48;
  int c = tid >> 1, chv = tid & 1;
  int g = c >> 6, hh = c & 63;
  const unsigned short* src = base + (size_t)((g << 8) + (n << 6) + hh)*48;
  unsigned short* dst = gx + (hh >> 2)*640 + (((hh & 3) << 2) + g)*40;
  if (chv == 0){
    *(uint4*)(dst)      = *(const uint4*)(src);
    *(uint4*)(dst + 8)  = *(const uint4*)(src + 8);
    *(uint2*)(dst + 16) = *(const uint2*)(src + 16);
  } else {
    const unsigned short* s3 = src + 24 + smin;
    dst[24] = s3[0]; dst[25] = s3[1]; dst[26] = s3[2]; dst[27] = s3[3];
  }
}

__global__ __launch_bounds__(512, 4) void edge_lstm(
    const unsigned short* __restrict__ gsrT, const float* __restrict__ bceGI,
    const unsigned short* __restrict__ pWeh, const float* __restrict__ Wf,
    unsigned short* __restrict__ hb, float* __restrict__ Afin,
    unsigned int* __restrict__ ectr){
  __shared__ __align__(16) unsigned short hst[48*RS];      // 26880 B
  __shared__ __align__(16) unsigned short gxb[2][10240];   // 40960 B
  __shared__ __align__(16) float sbce[256];
  __shared__ __align__(16) float sWf[64];
  int tid = threadIdx.x, lane = tid & 63, w = tid >> 6;
  int l15 = lane & 15, quad = lane >> 4;
  int bid = blockIdx.x;
  int n = bid >> 7, G = bid & 127, b = G >> 3, m = G & 7;
  int e0 = m*48;
  int valid = NEDGE - e0 < 48 ? NEDGE - e0 : 48;
  int smin = e0 / 19;
  unsigned int* ctr = ectr + G*32;

  uint4 wreg[2][8];
  #pragma unroll
  for (int tt = 0; tt < 2; ++tt)
    #pragma unroll
    for (int kt = 0; kt < 8; ++kt)
      wreg[tt][kt] = ((const uint4*)pWeh)[(((n*8 + w)*2 + tt)*8 + kt)*64 + lane];

  // one-hot A frags: k<20 -> receiver node k; k in [24,28) -> sender smin+(k-24)
  uint4 aoh[3];
  #pragma unroll
  for (int mt = 0; mt < 3; ++mt){
    int row = mt*16 + l15;
    int e = e0 + (row < valid ? row : valid-1);
    int s = e / 19; int rr = e - s*19;
    int sr = s - smin;
    int rc = rr + (rr >= s ? 1 : 0);
    unsigned int wd[4];
    #pragma unroll
    for (int p = 0; p < 4; ++p){
      int k0 = quad*8 + 2*p, k1 = k0 + 1;
      unsigned short a0 = ((k0 < 20) ? (rc == k0) : (k0 >= 24 && k0 < 28 && sr == k0-24)) ? 0x3F80 : 0;
      unsigned short a1 = ((k1 < 20) ? (rc == k1) : (k1 >= 24 && k1 < 28 && sr == k1-24)) ? 0x3F80 : 0;
      wd[p] = (unsigned int)a0 | ((unsigned int)a1 << 16);
    }
    aoh[mt] = make_uint4(wd[0], wd[1], wd[2], wd[3]);
  }

  if (tid < 256) sbce[tid] = bceGI[n*256 + tid];
  if (tid < 64)  sWf[tid]  = Wf[n*64 + tid];
  uint4 z4 = make_uint4(0,0,0,0);
  for (int i = tid; i < 1680; i += 512) ((uint4*)hst)[i] = z4;
  for (int i = tid; i < 2560; i += 512) ((uint4*)gxb)[i] = z4;
  __syncthreads();
  stage_gxb(gsrT, &gxb[0][0], tid, b, smin, n, 0);
  __syncthreads();

  float bb[2]  = { sbce[(w*2+0)*16 + l15], sbce[(w*2+1)*16 + l15] };
  float wfr[2] = { sWf[(w*2+0)*4 + (l15>>2)], sWf[(w*2+1)*4 + (l15>>2)] };

  float ce[2][3]; float epi[3];
  #pragma unroll
  for (int mt = 0; mt < 3; ++mt){ ce[0][mt] = 0.f; ce[1][mt] = 0.f; epi[mt] = 0.f; }

  for (int t = 0; t < TSTEPS; ++t){
    int par = t & 1, nxt = par ^ 1;
    if (t > 0){
      if (tid == 0){
        unsigned int tgt = 4u*(unsigned)t;
        while (__hip_atomic_load(ctr, __ATOMIC_RELAXED, __HIP_MEMORY_SCOPE_AGENT) < tgt)
          __builtin_amdgcn_s_sleep(1);
      }
      __syncthreads();                                    // B1
      const unsigned long long* hbp = (const unsigned long long*)hb
          + (((size_t)((t-1)&1)*16 + b)*8 + m)*48*64;
      unsigned long long pv[5]; int po[5] = {-1,-1,-1,-1,-1};
      #pragma unroll
      for (int j = 0; j < 5; ++j){
        int i = tid + j*512;                   // 0..2303: 3 partner slices x 768 ull
        if (i < 2304){
          int which = i / 768, jj = i - which*768;
          int r = jj >> 4, c = jj & 15;
          int np = which + (which >= n ? 1 : 0);
          pv[j] = load_ax(&hbp[(size_t)r*64 + np*16 + c]);
          po[j] = r*RS + np*64 + c*4;
        }
      }
      #pragma unroll
      for (int j = 0; j < 5; ++j)
        if (po[j] >= 0) *(unsigned long long*)&hst[po[j]] = pv[j];
    }
    if (t + 1 < TSTEPS)
      stage_gxb(gsrT, &gxb[nxt][0], tid, b, smin, n, t+1);
    __syncthreads();                                      // B2

    f32x4 acc[2][3];
    #pragma unroll
    for (int mt = 0; mt < 3; ++mt){
      acc[0][mt] = (f32x4){bb[0],bb[0],bb[0],bb[0]};
      acc[1][mt] = (f32x4){bb[1],bb[1],bb[1],bb[1]};
    }
    #pragma unroll
    for (int kt = 0; kt < 8; ++kt){
      bf16x8 a[3];
      #pragma unroll
      for (int mt = 0; mt < 3; ++mt)
        a[mt] = as_frag(*(const uint4*)&hst[(mt*16 + l15)*RS + kt*32 + quad*8]);
      #pragma unroll
      for (int mt = 0; mt < 3; ++mt){
        acc[0][mt] = __builtin_amdgcn_mfma_f32_16x16x32_bf16(a[mt], as_frag(wreg[0][kt]), acc[0][mt], 0, 0, 0);
        acc[1][mt] = __builtin_amdgcn_mfma_f32_16x16x32_bf16(a[mt], as_frag(wreg[1][kt]), acc[1][mt], 0, 0, 0);
      }
    }
    {
      bf16x8 bx0 = as_frag(*(const uint4*)&gxb[par][(w*2+0)*640 + l15*40 + quad*8]);
      bf16x8 bx1 = as_frag(*(const uint4*)&gxb[par][(w*2+1)*640 + l15*40 + quad*8]);
      #pragma unroll
      for (int mt = 0; mt < 3; ++mt){
        acc[0][mt] = __builtin_amdgcn_mfma_f32_16x16x32_bf16(as_frag(aoh[mt]), bx0, acc[0][mt], 0, 0, 0);
        acc[1][mt] = __builtin_amdgcn_mfma_f32_16x16x32_bf16(as_frag(aoh[mt]), bx1, acc[1][mt], 0, 0, 0);
      }
    }
    __syncthreads();                                      // B3 (hst reads done)

    #pragma unroll
    for (int tt = 0; tt < 2; ++tt){
      int tl = w*2 + tt;
      #pragma unroll
      for (int mt = 0; mt < 3; ++mt){
        f32x4 v = acc[tt][mt];
        xpose4(v, l15);
        float iv = sigmf(v[0]), fv = sigmf(v[1]), gg = tanh_f(v[2]), ov = sigmf(v[3]);
        float cc = fv*ce[tt][mt] + iv*gg; ce[tt][mt] = cc;
        float h = ov*tanh_f(cc);
        if (t < 62){
          int row = mt*16 + quad*4 + (l15 & 3);
          hst[row*RS + n*64 + tl*4 + (l15>>2)] = f2bf(h);
        } else {
          epi[mt] += h * wfr[tt];
        }
      }
    }
    if (t < 62){
      __syncthreads();                                    // B4 (h writes visible)
      unsigned long long* hbc = (unsigned long long*)hb
          + (((size_t)(t&1)*16 + b)*8 + m)*48*64;
      #pragma unroll
      for (int j = 0; j < 2; ++j){
        int i = tid + j*512;                   // 0..767 ull, coalesced
        if (i < 768){
          int r = i >> 4, c = i & 15;
          unsigned long long v = *(const unsigned long long*)&hst[r*RS + n*64 + c*4];
          store_ax(&hbc[(size_t)r*64 + n*16 + c], v);
        }
      }
      wait_vm0();
      __syncthreads();                                    // B5
      if (tid == 0)
        __hip_atomic_fetch_add(ctr, 1u, __ATOMIC_RELAXED, __HIP_MEMORY_SCOPE_AGENT);
    }
  }
  // epilogue: reduce over hsub lanes (xor 4, 8), one atomic per (row, wave)
  #pragma unroll
  for (int mt = 0; mt < 3; ++mt){
    float v = epi[mt];
    v += __shfl_xor(v, 4);
    v += __shfl_xor(v, 8);
    if (l15 < 4){
      int row = mt*16 + quad*4 + l15;
      if (row < valid)
        atomicAdd(&Afin[b*380 + e0 + row], v);
    }
  }
}

// ---------------------------------------------------------------------------
// finalize
__global__ __launch_bounds__(256) void finalize(const float* __restrict__ Afin,
                                                const float* __restrict__ bfp,
                                                float* __restrict__ out){
  int idx = blockIdx.x*256 + threadIdx.x;
  if (idx >= 16*400) return;
  int b = idx / 400; int ij = idx % 400; int i = ij / 20; int j = ij % 20;
  float v = 0.f;
  if (i != j){
    int e1 = i*19 + j - (j > i ? 1 : 0);
    int e2 = j*19 + i - (i > j ? 1 : 0);
    float bf = bfp[0];
    v = 0.5f*(sigmf(Afin[b*380 + e1] + bf) + sigmf(Afin[b*380 + e2] + bf));
  }
  out[idx] = v;
}

// ---------------------------------------------------------------------------
extern "C" void kernel_launch(void* const* d_in, const int* in_sizes, int n_in,
                              void* d_out, int out_size, void* d_ws, size_t ws_size,
                              hipStream_t stream){
  (void)in_sizes; (void)n_in; (void)out_size; (void)ws_size;
  const float* X   = (const float*)d_in[0];
  const float* Wm  = (const float*)d_in[3];
  const float* bm  = (const float*)d_in[4];
  const float* Wmi = (const float*)d_in[5];
  const float* bmi = (const float*)d_in[6];
  const float* Wmh = (const float*)d_in[7];
  const float* bmh = (const float*)d_in[8];
  const float* We  = (const float*)d_in[9];
  const float* be  = (const float*)d_in[10];
  const float* Wei = (const float*)d_in[11];
  const float* bei = (const float*)d_in[12];
  const float* Weh = (const float*)d_in[13];
  const float* beh = (const float*)d_in[14];
  const float* Wf  = (const float*)d_in[15];
  const float* bfp = (const float*)d_in[16];

  char* ws = (char*)d_ws;
  float* Wse   = (float*)(ws + 0);                          // 1 MB
  float* Wre   = (float*)(ws + 1048576);                    // 1 MB
  float* WcmGI = (float*)(ws + 2097152);                    // 16 KB
  float* bcmGI = (float*)(ws + 2113536);                    // 4 KB
  float* bceGI = (float*)(ws + 2117632);                    // 4 KB
  unsigned short* pWmh = (unsigned short*)(ws + 2121728);   // 512 KB
  unsigned short* pWeh = (unsigned short*)(ws + 2646016);   // 512 KB
  unsigned short* pWsr = (unsigned short*)(ws + 3170304);   // 1 MB
  unsigned short* hm   = (unsigned short*)(ws + 4218880);   // 10.3 MB (t-major)
  unsigned short* gsrT = (unsigned short*)(ws + 14540800);  // 99.1 MB (16*63*1024 recs x 96 B)
  unsigned short* hb   = (unsigned short*)(ws + 113631232); // 6.3 MB (edge exchange)
  unsigned short* mb   = hb;                                // aliased: disjoint lifetime
  float* Afin          = (float*)(ws + 119922688);          // 24 KB
  unsigned int* ectr   = (unsigned int*)(ws + 119947264);   // 16 KB (128 groups x 128 B)
  unsigned int* mctr   = (unsigned int*)(ws + 119963648);   // 4 KB (32 groups x 128 B)
  float* out = (float*)d_out;

  hipLaunchKernelGGL(prep_a, dim3(2097), dim3(256), 0, stream,
                     We, Wei, Wm, Wmi, bm, bmi, bmh, be, bei, beh,
                     Wse, Wre, WcmGI, bcmGI, bceGI, Afin, ectr, mctr);
  hipLaunchKernelGGL(prep_b, dim3(512), dim3(256), 0, stream,
                     Wmh, Weh, Wse, Wre, pWmh, pWeh, pWsr);
  {
    void* margs[] = {(void*)&X, (void*)&WcmGI, (void*)&bcmGI, (void*)&pWmh,
                     (void*)&hm, (void*)&mb, (void*)&mctr};
    hipLaunchCooperativeKernel(reinterpret_cast<void*>(motion_lstm),
                               dim3(128), dim3(512), margs, 0, stream);
  }
  hipLaunchKernelGGL(gsr_gemm, dim3(252*16), dim3(256), 0, stream,
                     hm, pWsr, gsrT);
  {
    void* eargs[] = {(void*)&gsrT, (void*)&bceGI, (void*)&pWeh, (void*)&Wf,
                     (void*)&hb, (void*)&Afin, (void*)&ectr};
    hipLaunchCooperativeKernel(reinterpret_cast<void*>(edge_lstm),
                               dim3(512), dim3(512), eargs, 0, stream);
  }
  hipLaunchKernelGGL(finalize, dim3(25), dim3(256), 0, stream,
                     Afin, bfp, out);
}

// Round 10
// 1077.718 us; speedup vs baseline: 1.4014x; 1.4014x over previous
//
#include <hip/hip_runtime.h>
#include <stdint.h>

// Problem constants
#define NBATCH 16
#define NNODE  20
#define TSTEPS 63      // T-1
#define NEDGE  380
#define HID    256
#define RS     280     // hst row stride in shorts (16B-aligned rows, phase-clean b128)
#define SPIN_MAX (1u << 23)   // watchdog: bounded spin (deadlock -> visible wrong answer)

typedef __bf16 bf16x8 __attribute__((ext_vector_type(8)));
typedef float  f32x4  __attribute__((ext_vector_type(4)));

__device__ __forceinline__ float bf2f(unsigned short u){
  union { unsigned int i; float f; } v; v.i = ((unsigned int)u) << 16; return v.f;
}
__device__ __forceinline__ unsigned short f2bf(float f){
  union { float f; unsigned int i; } v; v.f = f;
  return (unsigned short)((v.i + 0x7FFFu + ((v.i >> 16) & 1u)) >> 16);
}
__device__ __forceinline__ bf16x8 as_frag(uint4 v){
  union { uint4 u; bf16x8 b; } c; c.u = v; return c.b;
}
__device__ __forceinline__ float sigmf(float x){ return 1.0f/(1.0f+__expf(-x)); }
__device__ __forceinline__ float tanh_f(float x){ float e=__expf(2.0f*x); return (e-1.0f)/(e+1.0f); }

// Relaxed agent-scope ops: per-access sc1 (LLC = coherence point), no cache-wide inv/wb.
__device__ __forceinline__ unsigned long long load_ax(const unsigned long long* p){
  return __hip_atomic_load(p, __ATOMIC_RELAXED, __HIP_MEMORY_SCOPE_AGENT);
}
__device__ __forceinline__ void store_ax(unsigned long long* p, unsigned long long v){
  __hip_atomic_store(p, v, __ATOMIC_RELAXED, __HIP_MEMORY_SCOPE_AGENT);
}
__device__ __forceinline__ void wait_vm0(){ asm volatile("s_waitcnt vmcnt(0)" ::: "memory"); }

__device__ __forceinline__ void spin_until(const unsigned int* ctr, unsigned int tgt){
  unsigned int guard = 0;
  while (__hip_atomic_load(ctr, __ATOMIC_RELAXED, __HIP_MEMORY_SCOPE_AGENT) < tgt){
    if (++guard > SPIN_MAX) break;
    __builtin_amdgcn_s_sleep(1);
  }
}

// In-register 4x4 gate transpose among lanes cl^1, cl^2 (gate-interleaved cols). [proven R4-R7]
__device__ __forceinline__ void xpose4(f32x4& v, int cl){
  float s0 = __shfl_xor((float)v[1], 1), s1 = __shfl_xor((float)v[0], 1);
  float s2 = __shfl_xor((float)v[3], 1), s3 = __shfl_xor((float)v[2], 1);
  bool b0 = (cl & 1);
  float a0 = b0 ? s0 : v[0], a1 = b0 ? v[1] : s1;
  float a2 = b0 ? s2 : v[2], a3 = b0 ? v[3] : s3;
  float t0 = __shfl_xor(a2, 2), t1 = __shfl_xor(a3, 2);
  float t2 = __shfl_xor(a0, 2), t3 = __shfl_xor(a1, 2);
  bool b1 = (cl & 2);
  v[0] = b1 ? t0 : a0; v[1] = b1 ? t1 : a1;
  v[2] = b1 ? a2 : t2; v[3] = b1 ? a3 : t3;
}

// Gather 4 bf16 h-values (cols tl*4+hsub, hsub = l15>>2) into one 8-B value on
// lanes with hsub==0. Two xor-shuffles; all lanes must execute.
__device__ __forceinline__ unsigned long long pack_h4(unsigned int hv, int l15){
  unsigned int o4 = (unsigned int)__shfl_xor((int)hv, 4);
  unsigned int lo = ((l15 & 4) == 0) ? ((hv & 0xffffu) | (o4 << 16))
                                     : ((o4 & 0xffffu) | (hv << 16));
  unsigned int hi = (unsigned int)__shfl_xor((int)lo, 8);
  return ((unsigned long long)hi << 32) | (unsigned long long)lo;
}

// ---------------------------------------------------------------------------
// prep_a: combined weights (fp32) + interleaved biases + zero counters/Afin.
__global__ __launch_bounds__(256) void prep_a(
    const float* __restrict__ We, const float* __restrict__ Wei,
    const float* __restrict__ Wm, const float* __restrict__ Wmi,
    const float* __restrict__ bm, const float* __restrict__ bmi, const float* __restrict__ bmh,
    const float* __restrict__ be, const float* __restrict__ bei, const float* __restrict__ beh,
    float* __restrict__ Wse, float* __restrict__ Wre, float* __restrict__ WcmGI,
    float* __restrict__ bcmGI, float* __restrict__ bceGI,
    float* __restrict__ Afin, unsigned int* __restrict__ ectr, unsigned int* __restrict__ mctr){
  int bid = blockIdx.x, tid = threadIdx.x;
  if (bid < 2048){
    int idx = bid*256 + tid;
    int half = idx >> 18;
    int j = idx & 262143;
    int k = j >> 10, nn = j & 1023;
    const float* Wrow = We + (half*256 + k)*128;
    float s = 0.f;
    for (int d = 0; d < 128; ++d) s += Wrow[d] * Wei[d*1024 + nn];
    (half ? Wre : Wse)[k*1024 + nn] = s;
  } else if (bid < 2064){
    int idx = (bid-2048)*256 + tid;
    int d = idx >> 10, ci = idx & 1023;
    int col = (ci & 3)*256 + (ci >> 2);
    float s = 0.f;
    for (int j = 0; j < 128; ++j) s += Wm[d*128 + j] * Wmi[j*1024 + col];
    WcmGI[idx] = s;
  } else if (bid < 2068){
    int ci = (bid-2064)*256 + tid;
    int col = (ci & 3)*256 + (ci >> 2);
    float s = bmi[col] + bmh[col];
    for (int j = 0; j < 128; ++j) s += bm[j] * Wmi[j*1024 + col];
    bcmGI[ci] = s;
  } else if (bid < 2072){
    int ci = (bid-2068)*256 + tid;
    int col = (ci & 3)*256 + (ci >> 2);
    float s = bei[col] + beh[col];
    for (int j = 0; j < 128; ++j) s += be[j] * Wei[j*1024 + col];
    bceGI[ci] = s;
  } else if (bid == 2072){
    for (int i = tid; i < 4096; i += 256) ectr[i] = 0u;   // 128-B padded groups
    for (int i = tid; i < 1024; i += 256) mctr[i] = 0u;
  } else {
    int idx = (bid-2073)*256 + tid;
    if (idx < NBATCH*NEDGE) Afin[idx] = 0.f;
  }
}

// ---------------------------------------------------------------------------
// prep_b packing (verified R2-R7).
__device__ __forceinline__ void pack_gi(const float* __restrict__ W,
                                        unsigned short* __restrict__ dst, int id){
  int lane = id & 63, kt = (id >> 6) & 7, tt = (id >> 9) & 1, w = (id >> 10) & 7, nb = id >> 13;
  int cl = lane & 15, q = lane >> 4;
  int gcol = (cl & 3)*256 + nb*64 + (w*2 + tt)*4 + (cl >> 2);
  int k0 = kt*32 + q*8;
  unsigned int wb[4];
  #pragma unroll
  for (int p = 0; p < 4; ++p){
    unsigned short a = f2bf(W[(k0+2*p  )*1024 + gcol]);
    unsigned short b = f2bf(W[(k0+2*p+1)*1024 + gcol]);
    wb[p] = (unsigned int)a | ((unsigned int)b << 16);
  }
  ((uint4*)dst)[id] = make_uint4(wb[0], wb[1], wb[2], wb[3]);
}

__device__ __forceinline__ void pack_one(const float* __restrict__ S,
                                         unsigned short* __restrict__ dst, int id, int n){
  int lane = id & 63, kt = (id >> 6) & 7;
  int k0 = kt*32 + ((lane >> 4) << 3);
  unsigned int wb[4];
  #pragma unroll
  for (int p = 0; p < 4; ++p){
    unsigned short a = f2bf(S[(k0+2*p  )*1024 + n]);
    unsigned short b = f2bf(S[(k0+2*p+1)*1024 + n]);
    wb[p] = (unsigned int)a | ((unsigned int)b << 16);
  }
  ((uint4*)dst)[id] = make_uint4(wb[0], wb[1], wb[2], wb[3]);
}

__global__ __launch_bounds__(256) void prep_b(
    const float* __restrict__ Wmh, const float* __restrict__ Weh,
    const float* __restrict__ Wse, const float* __restrict__ Wre,
    unsigned short* __restrict__ pWmh, unsigned short* __restrict__ pWeh,
    unsigned short* __restrict__ pWsr){
  int gid = blockIdx.x*256 + threadIdx.x;
  if (gid < 32768){
    pack_gi(Wmh, pWmh, gid);
  } else if (gid < 65536){
    pack_gi(Weh, pWeh, gid - 32768);
  } else {
    int id = gid - 65536;
    int ng = (id >> 9)*16 + (id & 15);
    const float* S = (ng < 1024) ? Wse : Wre;
    pack_one(S, pWsr, id, ng & 1023);
  }
}

// ---------------------------------------------------------------------------
// motion_lstm: grid 128 = 32 m (10 seqs) x 4 n. 512 thr = 8 waves.
// dbuf hst + register publish: 3 barriers/step (was 5).
__global__ __launch_bounds__(512, 2) void motion_lstm(
    const float* __restrict__ X, const float* __restrict__ WcmGI,
    const float* __restrict__ bcmGI, const unsigned short* __restrict__ pWmh,
    unsigned short* __restrict__ hm, unsigned short* __restrict__ mb,
    unsigned int* __restrict__ mctr){
  __shared__ __align__(16) unsigned short hst[2][16*RS];   // 17920 B
  __shared__ float dxs[10*252];
  __shared__ __align__(16) float sWc[4*256];
  __shared__ __align__(16) float sbc[256];
  int tid = threadIdx.x, lane = tid & 63, w = tid >> 6;
  int l15 = lane & 15, quad = lane >> 4;
  int m = blockIdx.x & 31, n = blockIdx.x >> 5;
  int s0 = m*10;
  unsigned int* ctr = mctr + m*32;

  uint4 wreg[2][8];
  #pragma unroll
  for (int tt = 0; tt < 2; ++tt)
    #pragma unroll
    for (int kt = 0; kt < 8; ++kt)
      wreg[tt][kt] = ((const uint4*)pWmh)[(((n*8 + w)*2 + tt)*8 + kt)*64 + lane];

  uint4 z4 = make_uint4(0,0,0,0);
  for (int i = tid; i < 1120; i += 512) ((uint4*)hst)[i] = z4;
  for (int i = tid; i < 1024; i += 512) sWc[i] = WcmGI[(i >> 8)*1024 + n*256 + (i & 255)];
  if (tid < 256) sbc[tid] = bcmGI[n*256 + tid];
  for (int i = tid; i < 2520; i += 512){
    int sl = i / 252; int r = i % 252; int t = r >> 2; int d = r & 3;
    const float* Xp = X + (((size_t)(s0 + sl)*64 + t)*4 + d);
    dxs[i] = Xp[4] - Xp[0];
  }
  __syncthreads();

  float bb[2] = { sbc[(w*2+0)*16 + l15], sbc[(w*2+1)*16 + l15] };
  int row = quad*4 + (l15 & 3);
  int hsub = l15 >> 2;
  int slr = row < 10 ? row : 9;
  float ce[2] = {0.f, 0.f};

  for (int t = 0; t < TSTEPS; ++t){
    int par = t & 1, nxt = par ^ 1;
    if (t > 0){
      if (tid == 0) spin_until(ctr, 4u*(unsigned)t);
      __syncthreads();                                    // B1
      const unsigned long long* mbp = (const unsigned long long*)mb
          + ((size_t)((t-1)&1)*32 + m)*16*64;
      unsigned long long pv[2]; int po[2] = {-1,-1};
      #pragma unroll
      for (int j = 0; j < 2; ++j){
        int i = tid + j*512;                   // 0..767: 3 partner slices x 256 ull
        if (i < 768){
          int which = i >> 8, jj = i & 255;
          int r = jj >> 4, c = jj & 15;
          int np = which + (which >= n ? 1 : 0);
          pv[j] = load_ax(&mbp[(size_t)r*64 + np*16 + c]);
          po[j] = r*RS + np*64 + c*4;
        }
      }
      #pragma unroll
      for (int j = 0; j < 2; ++j)
        if (po[j] >= 0) *(unsigned long long*)&hst[par][po[j]] = pv[j];
    }
    __syncthreads();                                      // B2

    f32x4 acc[2];
    acc[0] = (f32x4){bb[0],bb[0],bb[0],bb[0]};
    acc[1] = (f32x4){bb[1],bb[1],bb[1],bb[1]};
    #pragma unroll
    for (int kt = 0; kt < 8; ++kt){
      bf16x8 a = as_frag(*(const uint4*)&hst[par][l15*RS + kt*32 + quad*8]);
      acc[0] = __builtin_amdgcn_mfma_f32_16x16x32_bf16(a, as_frag(wreg[0][kt]), acc[0], 0, 0, 0);
      acc[1] = __builtin_amdgcn_mfma_f32_16x16x32_bf16(a, as_frag(wreg[1][kt]), acc[1], 0, 0, 0);
    }
    // no post-MFMA barrier: update targets hst[nxt]

    unsigned long long* mbc = (unsigned long long*)mb
        + ((size_t)(t&1)*32 + m)*16*64;
    f32x4 dxv = *(const f32x4*)&dxs[slr*252 + t*4];
    #pragma unroll
    for (int tt = 0; tt < 2; ++tt){
      int tl = w*2 + tt;
      f32x4 v = acc[tt];
      xpose4(v, l15);
      #pragma unroll
      for (int d = 0; d < 4; ++d){
        f32x4 wv = *(const f32x4*)&sWc[d*256 + tl*16 + hsub*4];
        v[0] += dxv[d]*wv[0]; v[1] += dxv[d]*wv[1];
        v[2] += dxv[d]*wv[2]; v[3] += dxv[d]*wv[3];
      }
      float iv = sigmf(v[0]), fv = sigmf(v[1]), gg = tanh_f(v[2]), ov = sigmf(v[3]);
      float cc = fv*ce[tt] + iv*gg; ce[tt] = cc;
      unsigned short hb16 = f2bf(ov*tanh_f(cc));
      if (t < 62) hst[nxt][row*RS + n*64 + tl*4 + hsub] = hb16;
      unsigned long long uv = pack_h4((unsigned int)hb16, l15);
      if ((l15 & 12) == 0){
        int r = quad*4 + l15;
        if (t < 62) store_ax(&mbc[(size_t)r*64 + n*16 + w*2 + tt], uv);
        if (r < 10){
          int seq = s0 + r;
          int b2 = seq / 20, nd = seq - b2*20;
          *(unsigned long long*)&hm[(((size_t)(b2*63 + t)*20) + nd)*256 + n*64 + tl*4] = uv;
        }
      }
    }
    if (t < 62){
      wait_vm0();
      __syncthreads();                                    // B-pub
      if (tid == 0)
        __hip_atomic_fetch_add(ctr, 1u, __ATOMIC_RELAXED, __HIP_MEMORY_SCOPE_AGENT);
    }
  }
}

// ---------------------------------------------------------------------------
// gsr_gemm: hm2 (t-major) @ [Wse|Wre] -> gsrT records, coalesced aligned writes.
// Record (48 shorts, 96 B) per (bt, gate-interleaved col):
//   shorts 0..19  = receiver proj (Wre) nodes 0..19
//   shorts 24..43 = sender  proj (Wse) nodes 0..19
__global__ __launch_bounds__(256) void gsr_gemm(
    const unsigned short* __restrict__ hm, const unsigned short* __restrict__ pWsr,
    unsigned short* __restrict__ gsrT){
  __shared__ __align__(16) unsigned short scol[128*100];   // [col][row], stride 100
  int tid = threadIdx.x, lane = tid & 63, wid = tid >> 6;
  int l15 = lane & 15, quad = lane >> 4;
  int bm = blockIdx.x % 252, bn = blockIdx.x / 252;
  int rowbase = bm*80;
  f32x4 acc[5][2] = {};
  #pragma unroll
  for (int kt = 0; kt < 8; ++kt){
    bf16x8 af[5];
    #pragma unroll
    for (int mt = 0; mt < 5; ++mt)
      af[mt] = as_frag(*(const uint4*)&hm[(size_t)(rowbase + mt*16 + l15)*256 + kt*32 + quad*8]);
    #pragma unroll
    for (int j = 0; j < 2; ++j){
      int ntg = bn*8 + wid*2 + j;
      bf16x8 bfr = as_frag(*(const uint4*)&pWsr[(((size_t)ntg*8 + kt)*64 + lane)*8]);
      #pragma unroll
      for (int mt = 0; mt < 5; ++mt)
        acc[mt][j] = __builtin_amdgcn_mfma_f32_16x16x32_bf16(af[mt], bfr, acc[mt][j], 0, 0, 0);
    }
  }
  #pragma unroll
  for (int mt = 0; mt < 5; ++mt)
    #pragma unroll
    for (int j = 0; j < 2; ++j){
      int colL = (wid*2 + j)*16 + l15;
      unsigned int p0 = (unsigned)f2bf(acc[mt][j][0]) | ((unsigned)f2bf(acc[mt][j][1]) << 16);
      unsigned int p1 = (unsigned)f2bf(acc[mt][j][2]) | ((unsigned)f2bf(acc[mt][j][3]) << 16);
      *(uint2*)&scol[colL*100 + mt*16 + quad*4] = make_uint2(p0, p1);
    }
  __syncthreads();
  int recv = bn >> 3;   // 0 = Wse (sender cols), 1 = Wre (receiver cols)
  int doff = recv ? 0 : 24;
  #pragma unroll
  for (int rep = 0; rep < 2; ++rep){
    int i = tid + rep*256;
    int btl = i >> 7, colL = i & 127;
    const unsigned short* sp = &scol[colL*100 + btl*20];
    uint2 u0 = *(const uint2*)(sp);
    uint2 u1 = *(const uint2*)(sp+4);
    uint2 u2 = *(const uint2*)(sp+8);
    uint2 u3 = *(const uint2*)(sp+12);
    uint2 u4 = *(const uint2*)(sp+16);
    unsigned short* dp = gsrT + ((size_t)(bm*4 + btl)*1024 + (bn&7)*128 + colL)*48 + doff;
    *(uint4*)(dp)      = make_uint4(u0.x, u0.y, u1.x, u1.y);
    *(uint4*)(dp + 8)  = make_uint4(u2.x, u2.y, u3.x, u3.y);
    *(uint2*)(dp + 16) = u4;
  }
}

// ---------------------------------------------------------------------------
// edge_lstm: grid 256 = 16 b x 4 m (95 edges) x 4 n. 512 thr = 8 waves.
// R6 tiling + dbuf hst + register publish: 3 barriers/step (was 5).
__device__ __forceinline__ void stage_gxb(const unsigned short* __restrict__ gsrT,
                                          unsigned short* __restrict__ gx,
                                          int tid, int b, int smin, int n, int tq){
  const unsigned short* base = gsrT + (size_t)(b*63 + tq)*1024*48;
  int c = tid >> 1, chv = tid & 1;
  int g = c >> 6, hh = c & 63;
  const unsigned short* src = base + (size_t)((g << 8) + (n << 6) + hh)*48;
  unsigned short* dst = gx + (hh >> 2)*640 + (((hh & 3) << 2) + g)*40;
  if (chv == 0){
    *(uint4*)(dst)      = *(const uint4*)(src);
    *(uint4*)(dst + 8)  = *(const uint4*)(src + 8);
    *(uint2*)(dst + 16) = *(const uint2*)(src + 16);
  } else {
    const unsigned short* s3 = src + 24 + smin;      // 5-sender window, unaligned-safe
    dst[24]=s3[0]; dst[25]=s3[1]; dst[26]=s3[2]; dst[27]=s3[3]; dst[28]=s3[4];
  }
}

__global__ __launch_bounds__(512, 2) void edge_lstm(
    const unsigned short* __restrict__ gsrT, const float* __restrict__ bceGI,
    const unsigned short* __restrict__ pWeh, const float* __restrict__ Wf,
    unsigned short* __restrict__ hb, float* __restrict__ Afin,
    unsigned int* __restrict__ ectr){
  __shared__ __align__(16) unsigned short hst[2][96*RS];   // 107520 B
  __shared__ __align__(16) unsigned short gxb[2][10240];   // 40960 B
  __shared__ __align__(16) float sbce[256];
  __shared__ __align__(16) float sWf[64];
  int tid = threadIdx.x, lane = tid & 63, w = tid >> 6;
  int l15 = lane & 15, quad = lane >> 4;
  int bid = blockIdx.x;
  int n = bid >> 6, G = bid & 63, b = G >> 2, m = G & 3;
  int e0 = m*95;
  unsigned int* ctr = ectr + G*32;

  uint4 wreg[2][8];
  #pragma unroll
  for (int tt = 0; tt < 2; ++tt)
    #pragma unroll
    for (int kt = 0; kt < 8; ++kt)
      wreg[tt][kt] = ((const uint4*)pWeh)[(((n*8 + w)*2 + tt)*8 + kt)*64 + lane];

  // one-hot A frags: k<20 -> receiver node k; k in [24,29) -> sender m*5+(k-24)
  uint4 aoh[6];
  #pragma unroll
  for (int mt = 0; mt < 6; ++mt){
    int row = mt*16 + l15;
    int e = e0 + (row < 95 ? row : 94);
    int s = e / 19; int rr = e - s*19;
    int sr = s - m*5;
    int rc = rr + (rr >= s ? 1 : 0);
    unsigned int wd[4];
    #pragma unroll
    for (int p = 0; p < 4; ++p){
      int k0 = quad*8 + 2*p, k1 = k0 + 1;
      unsigned short a0 = ((k0 < 20) ? (rc == k0) : (k0 >= 24 && k0 < 29 && sr == k0-24)) ? 0x3F80 : 0;
      unsigned short a1 = ((k1 < 20) ? (rc == k1) : (k1 >= 24 && k1 < 29 && sr == k1-24)) ? 0x3F80 : 0;
      wd[p] = (unsigned int)a0 | ((unsigned int)a1 << 16);
    }
    aoh[mt] = make_uint4(wd[0], wd[1], wd[2], wd[3]);
  }

  if (tid < 256) sbce[tid] = bceGI[n*256 + tid];
  if (tid < 64)  sWf[tid]  = Wf[n*64 + tid];
  uint4 z4 = make_uint4(0,0,0,0);
  for (int i = tid; i < 6720; i += 512) ((uint4*)hst)[i] = z4;
  for (int i = tid; i < 2560; i += 512) ((uint4*)gxb)[i] = z4;
  __syncthreads();
  stage_gxb(gsrT, &gxb[0][0], tid, b, m*5, n, 0);
  __syncthreads();

  float bb[2]  = { sbce[(w*2+0)*16 + l15], sbce[(w*2+1)*16 + l15] };
  float wfr[2] = { sWf[(w*2+0)*4 + (l15>>2)], sWf[(w*2+1)*4 + (l15>>2)] };

  float ce[2][6]; float epi[6];
  #pragma unroll
  for (int mt = 0; mt < 6; ++mt){ ce[0][mt] = 0.f; ce[1][mt] = 0.f; epi[mt] = 0.f; }

  for (int t = 0; t < TSTEPS; ++t){
    int par = t & 1, nxt = par ^ 1;
    if (t > 0){
      if (tid == 0) spin_until(ctr, 4u*(unsigned)t);
      __syncthreads();                                    // B1
      const unsigned long long* hbp = (const unsigned long long*)hb
          + (((size_t)((t-1)&1)*16 + b)*4 + m)*96*64;
      unsigned long long pv[9]; int po[9];
      #pragma unroll
      for (int j = 0; j < 9; ++j){
        int i = tid + j*512;                   // 0..4607: 3 partner slices x 1536 ull
        int which = i / 1536, jj = i - which*1536;
        int r = jj >> 4, c = jj & 15;
        int np = which + (which >= n ? 1 : 0);
        pv[j] = load_ax(&hbp[(size_t)r*64 + np*16 + c]);
        po[j] = r*RS + np*64 + c*4;
      }
      #pragma unroll
      for (int j = 0; j < 9; ++j)
        *(unsigned long long*)&hst[par][po[j]] = pv[j];
    }
    if (t + 1 < TSTEPS)
      stage_gxb(gsrT, &gxb[nxt][0], tid, b, m*5, n, t+1);
    __syncthreads();                                      // B2

    f32x4 acc[2][6];
    #pragma unroll
    for (int mt = 0; mt < 6; ++mt){
      acc[0][mt] = (f32x4){bb[0],bb[0],bb[0],bb[0]};
      acc[1][mt] = (f32x4){bb[1],bb[1],bb[1],bb[1]};
    }
    #pragma unroll
    for (int kt = 0; kt < 8; ++kt){
      bf16x8 a[6];
      #pragma unroll
      for (int mt = 0; mt < 6; ++mt)
        a[mt] = as_frag(*(const uint4*)&hst[par][(mt*16 + l15)*RS + kt*32 + quad*8]);
      #pragma unroll
      for (int mt = 0; mt < 6; ++mt){
        acc[0][mt] = __builtin_amdgcn_mfma_f32_16x16x32_bf16(a[mt], as_frag(wreg[0][kt]), acc[0][mt], 0, 0, 0);
        acc[1][mt] = __builtin_amdgcn_mfma_f32_16x16x32_bf16(a[mt], as_frag(wreg[1][kt]), acc[1][mt], 0, 0, 0);
      }
    }
    {
      bf16x8 bx0 = as_frag(*(const uint4*)&gxb[par][(w*2+0)*640 + l15*40 + quad*8]);
      bf16x8 bx1 = as_frag(*(const uint4*)&gxb[par][(w*2+1)*640 + l15*40 + quad*8]);
      #pragma unroll
      for (int mt = 0; mt < 6; ++mt){
        acc[0][mt] = __builtin_amdgcn_mfma_f32_16x16x32_bf16(as_frag(aoh[mt]), bx0, acc[0][mt], 0, 0, 0);
        acc[1][mt] = __builtin_amdgcn_mfma_f32_16x16x32_bf16(as_frag(aoh[mt]), bx1, acc[1][mt], 0, 0, 0);
      }
    }
    // no post-MFMA barrier: update targets hst[nxt]

    unsigned long long* hbc = (unsigned long long*)hb
        + (((size_t)(t&1)*16 + b)*4 + m)*96*64;
    #pragma unroll
    for (int tt = 0; tt < 2; ++tt){
      int tl = w*2 + tt;
      #pragma unroll
      for (int mt = 0; mt < 6; ++mt){
        f32x4 v = acc[tt][mt];
        xpose4(v, l15);
        float iv = sigmf(v[0]), fv = sigmf(v[1]), gg = tanh_f(v[2]), ov = sigmf(v[3]);
        float cc = fv*ce[tt][mt] + iv*gg; ce[tt][mt] = cc;
        float h = ov*tanh_f(cc);
        if (t < 62){
          unsigned short hb16 = f2bf(h);
          int row2 = mt*16 + quad*4 + (l15 & 3);
          hst[nxt][row2*RS + n*64 + tl*4 + (l15>>2)] = hb16;
          unsigned long long uv = pack_h4((unsigned int)hb16, l15);
          if ((l15 & 12) == 0)
            store_ax(&hbc[(size_t)(mt*16 + quad*4 + l15)*64 + n*16 + tl], uv);
        } else {
          epi[mt] += h * wfr[tt];
        }
      }
    }
    if (t < 62){
      wait_vm0();
      __syncthreads();                                    // B-pub
      if (tid == 0)
        __hip_atomic_fetch_add(ctr, 1u, __ATOMIC_RELAXED, __HIP_MEMORY_SCOPE_AGENT);
    }
  }
  // epilogue: reduce over hsub lanes (xor 4, 8), one atomic per (row, wave)
  #pragma unroll
  for (int mt = 0; mt < 6; ++mt){
    float v = epi[mt];
    v += __shfl_xor(v, 4);
    v += __shfl_xor(v, 8);
    if (l15 < 4){
      int row = mt*16 + quad*4 + l15;
      if (row < 95)
        atomicAdd(&Afin[b*380 + e0 + row], v);
    }
  }
}

// ---------------------------------------------------------------------------
// finalize
__global__ __launch_bounds__(256) void finalize(const float* __restrict__ Afin,
                                                const float* __restrict__ bfp,
                                                float* __restrict__ out){
  int idx = blockIdx.x*256 + threadIdx.x;
  if (idx >= 16*400) return;
  int b = idx / 400; int ij = idx % 400; int i = ij / 20; int j = ij % 20;
  float v = 0.f;
  if (i != j){
    int e1 = i*19 + j - (j > i ? 1 : 0);
    int e2 = j*19 + i - (i > j ? 1 : 0);
    float bf = bfp[0];
    v = 0.5f*(sigmf(Afin[b*380 + e1] + bf) + sigmf(Afin[b*380 + e2] + bf));
  }
  out[idx] = v;
}

// ---------------------------------------------------------------------------
extern "C" void kernel_launch(void* const* d_in, const int* in_sizes, int n_in,
                              void* d_out, int out_size, void* d_ws, size_t ws_size,
                              hipStream_t stream){
  (void)in_sizes; (void)n_in; (void)out_size; (void)ws_size;
  const float* X   = (const float*)d_in[0];
  const float* Wm  = (const float*)d_in[3];
  const float* bm  = (const float*)d_in[4];
  const float* Wmi = (const float*)d_in[5];
  const float* bmi = (const float*)d_in[6];
  const float* Wmh = (const float*)d_in[7];
  const float* bmh = (const float*)d_in[8];
  const float* We  = (const float*)d_in[9];
  const float* be  = (const float*)d_in[10];
  const float* Wei = (const float*)d_in[11];
  const float* bei = (const float*)d_in[12];
  const float* Weh = (const float*)d_in[13];
  const float* beh = (const float*)d_in[14];
  const float* Wf  = (const float*)d_in[15];
  const float* bfp = (const float*)d_in[16];

  char* ws = (char*)d_ws;
  float* Wse   = (float*)(ws + 0);                          // 1 MB
  float* Wre   = (float*)(ws + 1048576);                    // 1 MB
  float* WcmGI = (float*)(ws + 2097152);                    // 16 KB
  float* bcmGI = (float*)(ws + 2113536);                    // 4 KB
  float* bceGI = (float*)(ws + 2117632);                    // 4 KB
  unsigned short* pWmh = (unsigned short*)(ws + 2121728);   // 512 KB
  unsigned short* pWeh = (unsigned short*)(ws + 2646016);   // 512 KB
  unsigned short* pWsr = (unsigned short*)(ws + 3170304);   // 1 MB
  unsigned short* hm   = (unsigned short*)(ws + 4218880);   // 10.3 MB (t-major)
  unsigned short* gsrT = (unsigned short*)(ws + 14540800);  // 99.1 MB
  unsigned short* hb   = (unsigned short*)(ws + 113631232); // 6.3 MB (edge exchange)
  unsigned short* mb   = hb;                                // aliased: disjoint lifetime
  float* Afin          = (float*)(ws + 119922688);          // 24 KB
  unsigned int* ectr   = (unsigned int*)(ws + 119947264);   // 16 KB (padded groups)
  unsigned int* mctr   = (unsigned int*)(ws + 119963648);   // 4 KB (padded groups)
  float* out = (float*)d_out;

  hipLaunchKernelGGL(prep_a, dim3(2097), dim3(256), 0, stream,
                     We, Wei, Wm, Wmi, bm, bmi, bmh, be, bei, beh,
                     Wse, Wre, WcmGI, bcmGI, bceGI, Afin, ectr, mctr);
  hipLaunchKernelGGL(prep_b, dim3(512), dim3(256), 0, stream,
                     Wmh, Weh, Wse, Wre, pWmh, pWeh, pWsr);
  {
    void* margs[] = {(void*)&X, (void*)&WcmGI, (void*)&bcmGI, (void*)&pWmh,
                     (void*)&hm, (void*)&mb, (void*)&mctr};
    hipLaunchCooperativeKernel(reinterpret_cast<void*>(motion_lstm),
                               dim3(128), dim3(512), margs, 0, stream);
  }
  hipLaunchKernelGGL(gsr_gemm, dim3(252*16), dim3(256), 0, stream,
                     hm, pWsr, gsrT);
  {
    void* eargs[] = {(void*)&gsrT, (void*)&bceGI, (void*)&pWeh, (void*)&Wf,
                     (void*)&hb, (void*)&Afin, (void*)&ectr};
    hipLaunchCooperativeKernel(reinterpret_cast<void*>(edge_lstm),
                               dim3(256), dim3(512), eargs, 0, stream);
  }
  hipLaunchKernelGGL(finalize, dim3(25), dim3(256), 0, stream,
                     Afin, bfp, out);
}

// Round 11
// 1066.323 us; speedup vs baseline: 1.4164x; 1.0107x over previous
//
#include <hip/hip_runtime.h>
#include <stdint.h>

// Problem constants
#define NBATCH 16
#define NNODE  20
#define TSTEPS 63      // T-1
#define NEDGE  380
#define HID    256
#define RS     280     // hst row stride in shorts (16B-aligned rows, phase-clean b128)
#define SPIN_MAX (1u << 20)   // watchdog: bounded spin (~8 ms/step worst case)
#define POISON  0xAAAAAAAAAAAAAAAAull   // matches harness 0xAA pre-poison; f2bf never emits it

typedef __bf16 bf16x8 __attribute__((ext_vector_type(8)));
typedef float  f32x4  __attribute__((ext_vector_type(4)));

__device__ __forceinline__ float bf2f(unsigned short u){
  union { unsigned int i; float f; } v; v.i = ((unsigned int)u) << 16; return v.f;
}
__device__ __forceinline__ unsigned short f2bf(float f){
  union { float f; unsigned int i; } v; v.f = f;
  return (unsigned short)((v.i + 0x7FFFu + ((v.i >> 16) & 1u)) >> 16);
}
__device__ __forceinline__ bf16x8 as_frag(uint4 v){
  union { uint4 u; bf16x8 b; } c; c.u = v; return c.b;
}
__device__ __forceinline__ float sigmf(float x){ return 1.0f/(1.0f+__expf(-x)); }
__device__ __forceinline__ float tanh_f(float x){ float e=__expf(2.0f*x); return (e-1.0f)/(e+1.0f); }

// Relaxed agent-scope ops: per-access sc1 (LLC = coherence point), no cache-wide inv/wb.
__device__ __forceinline__ unsigned long long load_ax(const unsigned long long* p){
  return __hip_atomic_load(p, __ATOMIC_RELAXED, __HIP_MEMORY_SCOPE_AGENT);
}
__device__ __forceinline__ void store_ax(unsigned long long* p, unsigned long long v){
  __hip_atomic_store(p, v, __ATOMIC_RELAXED, __HIP_MEMORY_SCOPE_AGENT);
}

// In-register 4x4 gate transpose among lanes cl^1, cl^2 (gate-interleaved cols). [proven R4-R10]
__device__ __forceinline__ void xpose4(f32x4& v, int cl){
  float s0 = __shfl_xor((float)v[1], 1), s1 = __shfl_xor((float)v[0], 1);
  float s2 = __shfl_xor((float)v[3], 1), s3 = __shfl_xor((float)v[2], 1);
  bool b0 = (cl & 1);
  float a0 = b0 ? s0 : v[0], a1 = b0 ? v[1] : s1;
  float a2 = b0 ? s2 : v[2], a3 = b0 ? v[3] : s3;
  float t0 = __shfl_xor(a2, 2), t1 = __shfl_xor(a3, 2);
  float t2 = __shfl_xor(a0, 2), t3 = __shfl_xor(a1, 2);
  bool b1 = (cl & 2);
  v[0] = b1 ? t0 : a0; v[1] = b1 ? t1 : a1;
  v[2] = b1 ? a2 : t2; v[3] = b1 ? a3 : t3;
}

// ---------------------------------------------------------------------------
// prep_a: combined weights (fp32) + interleaved biases + zero Afin + poison
// exchange buffers (sentinel scheme). grid 4592.
__global__ __launch_bounds__(256) void prep_a(
    const float* __restrict__ We, const float* __restrict__ Wei,
    const float* __restrict__ Wm, const float* __restrict__ Wmi,
    const float* __restrict__ bm, const float* __restrict__ bmi, const float* __restrict__ bmh,
    const float* __restrict__ be, const float* __restrict__ bei, const float* __restrict__ beh,
    float* __restrict__ Wse, float* __restrict__ Wre, float* __restrict__ WcmGI,
    float* __restrict__ bcmGI, float* __restrict__ bceGI,
    float* __restrict__ Afin, uint4* __restrict__ hb3q, uint4* __restrict__ mb3q){
  int bid = blockIdx.x, tid = threadIdx.x;
  if (bid < 2048){
    int idx = bid*256 + tid;
    int half = idx >> 18;
    int j = idx & 262143;
    int k = j >> 10, nn = j & 1023;
    const float* Wrow = We + (half*256 + k)*128;
    float s = 0.f;
    for (int d = 0; d < 128; ++d) s += Wrow[d] * Wei[d*1024 + nn];
    (half ? Wre : Wse)[k*1024 + nn] = s;
  } else if (bid < 2064){
    int idx = (bid-2048)*256 + tid;
    int d = idx >> 10, ci = idx & 1023;
    int col = (ci & 3)*256 + (ci >> 2);
    float s = 0.f;
    for (int j = 0; j < 128; ++j) s += Wm[d*128 + j] * Wmi[j*1024 + col];
    WcmGI[idx] = s;
  } else if (bid < 2068){
    int ci = (bid-2064)*256 + tid;
    int col = (ci & 3)*256 + (ci >> 2);
    float s = bmi[col] + bmh[col];
    for (int j = 0; j < 128; ++j) s += bm[j] * Wmi[j*1024 + col];
    bcmGI[ci] = s;
  } else if (bid < 2072){
    int ci = (bid-2068)*256 + tid;
    int col = (ci & 3)*256 + (ci >> 2);
    float s = bei[col] + beh[col];
    for (int j = 0; j < 128; ++j) s += be[j] * Wei[j*1024 + col];
    bceGI[ci] = s;
  } else if (bid < 2096){
    int idx = (bid-2072)*256 + tid;
    if (idx < NBATCH*NEDGE) Afin[idx] = 0.f;
  } else {
    int idx = (bid-2096)*256 + tid;
    uint4 P = make_uint4(0xAAAAAAAAu,0xAAAAAAAAu,0xAAAAAAAAu,0xAAAAAAAAu);
    if (idx < 589824) hb3q[idx] = P;                 // hb3: 3 x 64 x 96 x 64 ull
    else if (idx < 638976) mb3q[idx-589824] = P;     // mb3: 3 x 32 x 16 x 64 ull
  }
}

// ---------------------------------------------------------------------------
// prep_b packing (verified R2-R10).
__device__ __forceinline__ void pack_gi(const float* __restrict__ W,
                                        unsigned short* __restrict__ dst, int id){
  int lane = id & 63, kt = (id >> 6) & 7, tt = (id >> 9) & 1, w = (id >> 10) & 7, nb = id >> 13;
  int cl = lane & 15, q = lane >> 4;
  int gcol = (cl & 3)*256 + nb*64 + (w*2 + tt)*4 + (cl >> 2);
  int k0 = kt*32 + q*8;
  unsigned int wb[4];
  #pragma unroll
  for (int p = 0; p < 4; ++p){
    unsigned short a = f2bf(W[(k0+2*p  )*1024 + gcol]);
    unsigned short b = f2bf(W[(k0+2*p+1)*1024 + gcol]);
    wb[p] = (unsigned int)a | ((unsigned int)b << 16);
  }
  ((uint4*)dst)[id] = make_uint4(wb[0], wb[1], wb[2], wb[3]);
}

__device__ __forceinline__ void pack_one(const float* __restrict__ S,
                                         unsigned short* __restrict__ dst, int id, int n){
  int lane = id & 63, kt = (id >> 6) & 7;
  int k0 = kt*32 + ((lane >> 4) << 3);
  unsigned int wb[4];
  #pragma unroll
  for (int p = 0; p < 4; ++p){
    unsigned short a = f2bf(S[(k0+2*p  )*1024 + n]);
    unsigned short b = f2bf(S[(k0+2*p+1)*1024 + n]);
    wb[p] = (unsigned int)a | ((unsigned int)b << 16);
  }
  ((uint4*)dst)[id] = make_uint4(wb[0], wb[1], wb[2], wb[3]);
}

__global__ __launch_bounds__(256) void prep_b(
    const float* __restrict__ Wmh, const float* __restrict__ Weh,
    const float* __restrict__ Wse, const float* __restrict__ Wre,
    unsigned short* __restrict__ pWmh, unsigned short* __restrict__ pWeh,
    unsigned short* __restrict__ pWsr){
  int gid = blockIdx.x*256 + threadIdx.x;
  if (gid < 32768){
    pack_gi(Wmh, pWmh, gid);
  } else if (gid < 65536){
    pack_gi(Weh, pWeh, gid - 32768);
  } else {
    int id = gid - 65536;
    int ng = (id >> 9)*16 + (id & 15);
    const float* S = (ng < 1024) ? Wse : Wre;
    pack_one(S, pWsr, id, ng & 1023);
  }
}

// ---------------------------------------------------------------------------
// motion_lstm: grid 128 = 32 m (10 seqs) x 4 n. 512 thr = 8 waves.
// R6 body + data-sentinel sync (3-parity rotation, producer poisons t-2 slice).
__global__ __launch_bounds__(512, 2) void motion_lstm(
    const float* __restrict__ X, const float* __restrict__ WcmGI,
    const float* __restrict__ bcmGI, const unsigned short* __restrict__ pWmh,
    unsigned short* __restrict__ hm, unsigned long long* __restrict__ mb3){
  __shared__ __align__(16) unsigned short hst[16*RS];
  __shared__ float dxs[10*252];
  __shared__ __align__(16) float sWc[4*256];
  __shared__ __align__(16) float sbc[256];
  int tid = threadIdx.x, lane = tid & 63, w = tid >> 6;
  int l15 = lane & 15, quad = lane >> 4;
  int m = blockIdx.x & 31, n = blockIdx.x >> 5;
  int s0 = m*10;

  uint4 wreg[2][8];
  #pragma unroll
  for (int tt = 0; tt < 2; ++tt)
    #pragma unroll
    for (int kt = 0; kt < 8; ++kt)
      wreg[tt][kt] = ((const uint4*)pWmh)[(((n*8 + w)*2 + tt)*8 + kt)*64 + lane];

  uint4 z4 = make_uint4(0,0,0,0);
  for (int i = tid; i < 560; i += 512) ((uint4*)hst)[i] = z4;
  for (int i = tid; i < 1024; i += 512) sWc[i] = WcmGI[(i >> 8)*1024 + n*256 + (i & 255)];
  if (tid < 256) sbc[tid] = bcmGI[n*256 + tid];
  for (int i = tid; i < 2520; i += 512){
    int sl = i / 252; int r = i % 252; int t = r >> 2; int d = r & 3;
    const float* Xp = X + (((size_t)(s0 + sl)*64 + t)*4 + d);
    dxs[i] = Xp[4] - Xp[0];
  }
  __syncthreads();

  float bb[2] = { sbc[(w*2+0)*16 + l15], sbc[(w*2+1)*16 + l15] };
  int row = quad*4 + (l15 & 3);
  int hsub = l15 >> 2;
  int slr = row < 10 ? row : 9;
  float ce[2] = {0.f, 0.f};

  for (int t = 0; t < TSTEPS; ++t){
    if (t > 0){
      const unsigned long long* mbp = mb3 + ((size_t)((t-1)%3)*32 + m)*1024;
      unsigned long long pv[2]; int off[2], po[2] = {-1,-1};
      #pragma unroll
      for (int j = 0; j < 2; ++j){
        int i = tid + j*512;                   // 0..767: 3 partner slices x 256 ull
        if (i < 768){
          int which = i >> 8, jj = i & 255;
          int r = jj >> 4, c = jj & 15;
          int np = which + (which >= n ? 1 : 0);
          off[j] = r*64 + np*16 + c;
          po[j]  = r*RS + np*64 + c*4;
          pv[j]  = POISON;
        }
      }
      unsigned int guard = 0; bool need = true;
      while (need){
        need = false;
        #pragma unroll
        for (int j = 0; j < 2; ++j)
          if (po[j] >= 0 && pv[j] == POISON) pv[j] = load_ax(&mbp[off[j]]);
        #pragma unroll
        for (int j = 0; j < 2; ++j)
          if (po[j] >= 0 && pv[j] == POISON) need = true;
        if (need){
          if (++guard > SPIN_MAX) break;
          __builtin_amdgcn_s_sleep(1);
        }
      }
      #pragma unroll
      for (int j = 0; j < 2; ++j)
        if (po[j] >= 0) *(unsigned long long*)&hst[po[j]] = pv[j];
      if (t >= 2 && tid < 256){                // poison own slice of parity (t-2)%3
        unsigned long long* mbq = mb3 + ((size_t)((t-2)%3)*32 + m)*1024;
        store_ax(&mbq[(size_t)(tid>>4)*64 + n*16 + (tid&15)], POISON);
      }
    }
    __syncthreads();                                      // B2 (drains poison+prev publish)

    f32x4 acc[2];
    acc[0] = (f32x4){bb[0],bb[0],bb[0],bb[0]};
    acc[1] = (f32x4){bb[1],bb[1],bb[1],bb[1]};
    #pragma unroll
    for (int kt = 0; kt < 8; ++kt){
      bf16x8 a = as_frag(*(const uint4*)&hst[l15*RS + kt*32 + quad*8]);
      acc[0] = __builtin_amdgcn_mfma_f32_16x16x32_bf16(a, as_frag(wreg[0][kt]), acc[0], 0, 0, 0);
      acc[1] = __builtin_amdgcn_mfma_f32_16x16x32_bf16(a, as_frag(wreg[1][kt]), acc[1], 0, 0, 0);
    }
    __syncthreads();                                      // B3 (hst reads done)

    f32x4 dxv = *(const f32x4*)&dxs[slr*252 + t*4];
    #pragma unroll
    for (int tt = 0; tt < 2; ++tt){
      int tl = w*2 + tt;
      f32x4 v = acc[tt];
      xpose4(v, l15);
      #pragma unroll
      for (int d = 0; d < 4; ++d){
        f32x4 wv = *(const f32x4*)&sWc[d*256 + tl*16 + hsub*4];
        v[0] += dxv[d]*wv[0]; v[1] += dxv[d]*wv[1];
        v[2] += dxv[d]*wv[2]; v[3] += dxv[d]*wv[3];
      }
      float iv = sigmf(v[0]), fv = sigmf(v[1]), gg = tanh_f(v[2]), ov = sigmf(v[3]);
      float cc = fv*ce[tt] + iv*gg; ce[tt] = cc;
      hst[row*RS + n*64 + tl*4 + hsub] = f2bf(ov*tanh_f(cc));
    }
    __syncthreads();                                      // B4 (h writes visible)

    unsigned long long* mbc = mb3 + ((size_t)(t%3)*32 + m)*1024;
    if (tid < 256){
      int r = tid >> 4, c = tid & 15;
      unsigned long long v = *(const unsigned long long*)&hst[r*RS + n*64 + c*4];
      if (t < 62) store_ax(&mbc[(size_t)r*64 + n*16 + c], v);   // fire-and-forget
      if (r < 10){
        int seq = s0 + r;
        int b2 = seq / 20, nd = seq - b2*20;
        *(unsigned long long*)&hm[(((size_t)(b2*63 + t)*20) + nd)*256 + n*64 + c*4] = v;
      }
    }
    // no drain, no counter: consumers poll the data words themselves
  }
}

// ---------------------------------------------------------------------------
// gsr_gemm: hm (t-major) @ [Wse|Wre] -> gsrT records (40 shorts, 80 B):
//   shorts 0..19  = receiver proj (Wre) nodes 0..19
//   shorts 20..39 = sender  proj (Wse) nodes 0..19
__global__ __launch_bounds__(256) void gsr_gemm(
    const unsigned short* __restrict__ hm, const unsigned short* __restrict__ pWsr,
    unsigned short* __restrict__ gsrT){
  __shared__ __align__(16) unsigned short scol[128*100];   // [col][row], stride 100
  int tid = threadIdx.x, lane = tid & 63, wid = tid >> 6;
  int l15 = lane & 15, quad = lane >> 4;
  int bm = blockIdx.x % 252, bn = blockIdx.x / 252;
  int rowbase = bm*80;
  f32x4 acc[5][2] = {};
  #pragma unroll
  for (int kt = 0; kt < 8; ++kt){
    bf16x8 af[5];
    #pragma unroll
    for (int mt = 0; mt < 5; ++mt)
      af[mt] = as_frag(*(const uint4*)&hm[(size_t)(rowbase + mt*16 + l15)*256 + kt*32 + quad*8]);
    #pragma unroll
    for (int j = 0; j < 2; ++j){
      int ntg = bn*8 + wid*2 + j;
      bf16x8 bfr = as_frag(*(const uint4*)&pWsr[(((size_t)ntg*8 + kt)*64 + lane)*8]);
      #pragma unroll
      for (int mt = 0; mt < 5; ++mt)
        acc[mt][j] = __builtin_amdgcn_mfma_f32_16x16x32_bf16(af[mt], bfr, acc[mt][j], 0, 0, 0);
    }
  }
  #pragma unroll
  for (int mt = 0; mt < 5; ++mt)
    #pragma unroll
    for (int j = 0; j < 2; ++j){
      int colL = (wid*2 + j)*16 + l15;
      unsigned int p0 = (unsigned)f2bf(acc[mt][j][0]) | ((unsigned)f2bf(acc[mt][j][1]) << 16);
      unsigned int p1 = (unsigned)f2bf(acc[mt][j][2]) | ((unsigned)f2bf(acc[mt][j][3]) << 16);
      *(uint2*)&scol[colL*100 + mt*16 + quad*4] = make_uint2(p0, p1);
    }
  __syncthreads();
  int recv = bn >> 3;   // 1 = Wre (receiver cols, slots 0..19), 0 = Wse (sender, 20..39)
  #pragma unroll
  for (int rep = 0; rep < 2; ++rep){
    int i = tid + rep*256;
    int btl = i >> 7, colL = i & 127;
    const unsigned short* sp = &scol[colL*100 + btl*20];
    uint2 u0 = *(const uint2*)(sp);
    uint2 u1 = *(const uint2*)(sp+4);
    uint2 u2 = *(const uint2*)(sp+8);
    uint2 u3 = *(const uint2*)(sp+12);
    uint2 u4 = *(const uint2*)(sp+16);
    unsigned short* dp = gsrT + ((size_t)(bm*4 + btl)*1024 + (bn&7)*128 + colL)*40;
    if (recv){
      *(uint4*)(dp)      = make_uint4(u0.x, u0.y, u1.x, u1.y);   // 16B-aligned (80B recs)
      *(uint4*)(dp + 8)  = make_uint4(u2.x, u2.y, u3.x, u3.y);
      *(uint2*)(dp + 16) = u4;
    } else {
      unsigned short* dq = dp + 20;                              // +40 B: 8-aligned
      *(uint2*)(dq)      = u0;
      *(uint2*)(dq + 4)  = u1;
      *(uint2*)(dq + 8)  = u2;
      *(uint2*)(dq + 12) = u3;
      *(uint2*)(dq + 16) = u4;
    }
  }
}

// ---------------------------------------------------------------------------
// edge_lstm: grid 256 = 16 b x 4 m (95 edges) x 4 n. 512 thr = 8 waves.
// R6 body + data-sentinel sync. One-hot xg K-tile (k<20 recv node k,
// k=24+i sender node m*5+i).
__device__ __forceinline__ void stage_gxb(const unsigned short* __restrict__ gsrT,
                                          unsigned short* __restrict__ gx,
                                          int tid, int b, int smin, int n, int tq){
  const unsigned short* base = gsrT + (size_t)(b*63 + tq)*1024*40;
  int c = tid >> 1, chv = tid & 1;
  int g = c >> 6, hh = c & 63;
  const unsigned short* src = base + (size_t)((g << 8) + (n << 6) + hh)*40;
  unsigned short* dst = gx + (hh >> 2)*640 + (((hh & 3) << 2) + g)*40;
  if (chv == 0){
    *(uint4*)(dst)      = *(const uint4*)(src);        // recv slots 0..7
    *(uint4*)(dst + 8)  = *(const uint4*)(src + 8);    // 8..15
    *(uint2*)(dst + 16) = *(const uint2*)(src + 16);   // 16..19
  } else {
    const unsigned short* s3 = src + 20 + smin;        // 5-sender window
    dst[24]=s3[0]; dst[25]=s3[1]; dst[26]=s3[2]; dst[27]=s3[3]; dst[28]=s3[4];
  }
}

__global__ __launch_bounds__(512, 2) void edge_lstm(
    const unsigned short* __restrict__ gsrT, const float* __restrict__ bceGI,
    const unsigned short* __restrict__ pWeh, const float* __restrict__ Wf,
    unsigned long long* __restrict__ hb3, float* __restrict__ Afin){
  __shared__ __align__(16) unsigned short hst[96*RS];      // 53760 B
  __shared__ __align__(16) unsigned short gxb[2][10240];   // 40960 B
  __shared__ __align__(16) float sbce[256];
  __shared__ __align__(16) float sWf[64];
  int tid = threadIdx.x, lane = tid & 63, w = tid >> 6;
  int l15 = lane & 15, quad = lane >> 4;
  int bid = blockIdx.x;
  int n = bid >> 6, G = bid & 63, b = G >> 2, m = G & 3;
  int e0 = m*95;

  uint4 wreg[2][8];
  #pragma unroll
  for (int tt = 0; tt < 2; ++tt)
    #pragma unroll
    for (int kt = 0; kt < 8; ++kt)
      wreg[tt][kt] = ((const uint4*)pWeh)[(((n*8 + w)*2 + tt)*8 + kt)*64 + lane];

  // one-hot A frags: k<20 -> receiver node k; k in [24,29) -> sender m*5+(k-24)
  uint4 aoh[6];
  #pragma unroll
  for (int mt = 0; mt < 6; ++mt){
    int row = mt*16 + l15;
    int e = e0 + (row < 95 ? row : 94);
    int s = e / 19; int rr = e - s*19;
    int sr = s - m*5;
    int rc = rr + (rr >= s ? 1 : 0);
    unsigned int wd[4];
    #pragma unroll
    for (int p = 0; p < 4; ++p){
      int k0 = quad*8 + 2*p, k1 = k0 + 1;
      unsigned short a0 = ((k0 < 20) ? (rc == k0) : (k0 >= 24 && k0 < 29 && sr == k0-24)) ? 0x3F80 : 0;
      unsigned short a1 = ((k1 < 20) ? (rc == k1) : (k1 >= 24 && k1 < 29 && sr == k1-24)) ? 0x3F80 : 0;
      wd[p] = (unsigned int)a0 | ((unsigned int)a1 << 16);
    }
    aoh[mt] = make_uint4(wd[0], wd[1], wd[2], wd[3]);
  }

  if (tid < 256) sbce[tid] = bceGI[n*256 + tid];
  if (tid < 64)  sWf[tid]  = Wf[n*64 + tid];
  uint4 z4 = make_uint4(0,0,0,0);
  for (int i = tid; i < 3360; i += 512) ((uint4*)hst)[i] = z4;
  for (int i = tid; i < 2560; i += 512) ((uint4*)gxb)[i] = z4;
  __syncthreads();
  stage_gxb(gsrT, &gxb[0][0], tid, b, m*5, n, 0);
  __syncthreads();

  float bb[2]  = { sbce[(w*2+0)*16 + l15], sbce[(w*2+1)*16 + l15] };
  float wfr[2] = { sWf[(w*2+0)*4 + (l15>>2)], sWf[(w*2+1)*4 + (l15>>2)] };

  float ce[2][6]; float epi[6];
  #pragma unroll
  for (int mt = 0; mt < 6; ++mt){ ce[0][mt] = 0.f; ce[1][mt] = 0.f; epi[mt] = 0.f; }

  for (int t = 0; t < TSTEPS; ++t){
    int par = t & 1, nxt = par ^ 1;
    if (t > 0){
      const unsigned long long* hbp = hb3 + ((size_t)((t-1)%3)*64 + G)*6144;
      unsigned long long pv[9]; int off[9]; int po[9];
      #pragma unroll
      for (int j = 0; j < 9; ++j){
        int i = tid + j*512;                   // 0..4607: 3 partner slices x 1536 ull
        int which = i / 1536, jj = i - which*1536;
        int r = jj >> 4, c = jj & 15;
        int np = which + (which >= n ? 1 : 0);
        off[j] = r*64 + np*16 + c;
        po[j]  = r*RS + np*64 + c*4;
        pv[j]  = POISON;
      }
      unsigned int guard = 0; bool need = true;
      while (need){
        need = false;
        #pragma unroll
        for (int j = 0; j < 9; ++j)
          if (pv[j] == POISON) pv[j] = load_ax(&hbp[off[j]]);
        #pragma unroll
        for (int j = 0; j < 9; ++j)
          if (pv[j] == POISON) need = true;
        if (need){
          if (++guard > SPIN_MAX) break;
          __builtin_amdgcn_s_sleep(1);
        }
      }
      #pragma unroll
      for (int j = 0; j < 9; ++j)
        *(unsigned long long*)&hst[po[j]] = pv[j];
      if (t >= 2){                             // poison own slice of parity (t-2)%3
        unsigned long long* hbq = hb3 + ((size_t)((t-2)%3)*64 + G)*6144;
        #pragma unroll
        for (int j = 0; j < 3; ++j){
          int i = tid + j*512;
          store_ax(&hbq[(size_t)(i>>4)*64 + n*16 + (i&15)], POISON);
        }
      }
    }
    if (t + 1 < TSTEPS)
      stage_gxb(gsrT, &gxb[nxt][0], tid, b, m*5, n, t+1);
    __syncthreads();                                      // B2 (drains poison+prev publish)

    f32x4 acc[2][6];
    #pragma unroll
    for (int mt = 0; mt < 6; ++mt){
      acc[0][mt] = (f32x4){bb[0],bb[0],bb[0],bb[0]};
      acc[1][mt] = (f32x4){bb[1],bb[1],bb[1],bb[1]};
    }
    #pragma unroll
    for (int kt = 0; kt < 8; ++kt){
      bf16x8 a[6];
      #pragma unroll
      for (int mt = 0; mt < 6; ++mt)
        a[mt] = as_frag(*(const uint4*)&hst[(mt*16 + l15)*RS + kt*32 + quad*8]);
      #pragma unroll
      for (int mt = 0; mt < 6; ++mt){
        acc[0][mt] = __builtin_amdgcn_mfma_f32_16x16x32_bf16(a[mt], as_frag(wreg[0][kt]), acc[0][mt], 0, 0, 0);
        acc[1][mt] = __builtin_amdgcn_mfma_f32_16x16x32_bf16(a[mt], as_frag(wreg[1][kt]), acc[1][mt], 0, 0, 0);
      }
    }
    {
      bf16x8 bx0 = as_frag(*(const uint4*)&gxb[par][(w*2+0)*640 + l15*40 + quad*8]);
      bf16x8 bx1 = as_frag(*(const uint4*)&gxb[par][(w*2+1)*640 + l15*40 + quad*8]);
      #pragma unroll
      for (int mt = 0; mt < 6; ++mt){
        acc[0][mt] = __builtin_amdgcn_mfma_f32_16x16x32_bf16(as_frag(aoh[mt]), bx0, acc[0][mt], 0, 0, 0);
        acc[1][mt] = __builtin_amdgcn_mfma_f32_16x16x32_bf16(as_frag(aoh[mt]), bx1, acc[1][mt], 0, 0, 0);
      }
    }
    __syncthreads();                                      // B3 (hst reads done)

    #pragma unroll
    for (int tt = 0; tt < 2; ++tt){
      int tl = w*2 + tt;
      #pragma unroll
      for (int mt = 0; mt < 6; ++mt){
        f32x4 v = acc[tt][mt];
        xpose4(v, l15);
        float iv = sigmf(v[0]), fv = sigmf(v[1]), gg = tanh_f(v[2]), ov = sigmf(v[3]);
        float cc = fv*ce[tt][mt] + iv*gg; ce[tt][mt] = cc;
        float h = ov*tanh_f(cc);
        if (t < 62){
          int row = mt*16 + quad*4 + (l15 & 3);
          hst[row*RS + n*64 + tl*4 + (l15>>2)] = f2bf(h);
        } else {
          epi[mt] += h * wfr[tt];
        }
      }
    }
    if (t < 62){
      __syncthreads();                                    // B4 (h writes visible)
      unsigned long long* hbc = hb3 + ((size_t)(t%3)*64 + G)*6144;
      #pragma unroll
      for (int j = 0; j < 3; ++j){
        int i = tid + j*512;                   // coalesced 8B stores, full lines
        unsigned long long v = *(const unsigned long long*)&hst[(i>>4)*RS + n*64 + (i&15)*4];
        store_ax(&hbc[(size_t)(i>>4)*64 + n*16 + (i&15)], v);
      }
      // fire-and-forget: consumers poll the data words themselves
    }
  }
  // epilogue: reduce over hsub lanes (xor 4, 8), one atomic per (row, wave)
  #pragma unroll
  for (int mt = 0; mt < 6; ++mt){
    float v = epi[mt];
    v += __shfl_xor(v, 4);
    v += __shfl_xor(v, 8);
    if (l15 < 4){
      int row = mt*16 + quad*4 + l15;
      if (row < 95)
        atomicAdd(&Afin[b*380 + e0 + row], v);
    }
  }
}

// ---------------------------------------------------------------------------
// finalize
__global__ __launch_bounds__(256) void finalize(const float* __restrict__ Afin,
                                                const float* __restrict__ bfp,
                                                float* __restrict__ out){
  int idx = blockIdx.x*256 + threadIdx.x;
  if (idx >= 16*400) return;
  int b = idx / 400; int ij = idx % 400; int i = ij / 20; int j = ij % 20;
  float v = 0.f;
  if (i != j){
    int e1 = i*19 + j - (j > i ? 1 : 0);
    int e2 = j*19 + i - (i > j ? 1 : 0);
    float bf = bfp[0];
    v = 0.5f*(sigmf(Afin[b*380 + e1] + bf) + sigmf(Afin[b*380 + e2] + bf));
  }
  out[idx] = v;
}

// ---------------------------------------------------------------------------
extern "C" void kernel_launch(void* const* d_in, const int* in_sizes, int n_in,
                              void* d_out, int out_size, void* d_ws, size_t ws_size,
                              hipStream_t stream){
  (void)in_sizes; (void)n_in; (void)out_size; (void)ws_size;
  const float* X   = (const float*)d_in[0];
  const float* Wm  = (const float*)d_in[3];
  const float* bm  = (const float*)d_in[4];
  const float* Wmi = (const float*)d_in[5];
  const float* bmi = (const float*)d_in[6];
  const float* Wmh = (const float*)d_in[7];
  const float* bmh = (const float*)d_in[8];
  const float* We  = (const float*)d_in[9];
  const float* be  = (const float*)d_in[10];
  const float* Wei = (const float*)d_in[11];
  const float* bei = (const float*)d_in[12];
  const float* Weh = (const float*)d_in[13];
  const float* beh = (const float*)d_in[14];
  const float* Wf  = (const float*)d_in[15];
  const float* bfp = (const float*)d_in[16];

  char* ws = (char*)d_ws;
  float* Wse   = (float*)(ws + 0);                          // 1 MB
  float* Wre   = (float*)(ws + 1048576);                    // 1 MB
  float* WcmGI = (float*)(ws + 2097152);                    // 16 KB
  float* bcmGI = (float*)(ws + 2113536);                    // 4 KB
  float* bceGI = (float*)(ws + 2117632);                    // 4 KB
  unsigned short* pWmh = (unsigned short*)(ws + 2121728);   // 512 KB
  unsigned short* pWeh = (unsigned short*)(ws + 2646016);   // 512 KB
  unsigned short* pWsr = (unsigned short*)(ws + 3170304);   // 1 MB
  unsigned short* hm   = (unsigned short*)(ws + 4218880);   // 10.3 MB (t-major)
  unsigned short* gsrT = (unsigned short*)(ws + 14540800);  // 82.6 MB (40-short recs)
  unsigned long long* hb3 = (unsigned long long*)(ws + 97116160); // 9.44 MB (3-parity)
  float* Afin          = (float*)(ws + 106553344);          // 24 KB
  unsigned long long* mb3 = (unsigned long long*)gsrT;      // 0.79 MB, aliased (disjoint lifetime)
  float* out = (float*)d_out;

  hipLaunchKernelGGL(prep_a, dim3(4592), dim3(256), 0, stream,
                     We, Wei, Wm, Wmi, bm, bmi, bmh, be, bei, beh,
                     Wse, Wre, WcmGI, bcmGI, bceGI, Afin,
                     (uint4*)hb3, (uint4*)mb3);
  hipLaunchKernelGGL(prep_b, dim3(512), dim3(256), 0, stream,
                     Wmh, Weh, Wse, Wre, pWmh, pWeh, pWsr);
  {
    void* margs[] = {(void*)&X, (void*)&WcmGI, (void*)&bcmGI, (void*)&pWmh,
                     (void*)&hm, (void*)&mb3};
    hipLaunchCooperativeKernel(reinterpret_cast<void*>(motion_lstm),
                               dim3(128), dim3(512), margs, 0, stream);
  }
  hipLaunchKernelGGL(gsr_gemm, dim3(252*16), dim3(256), 0, stream,
                     hm, pWsr, gsrT);
  {
    void* eargs[] = {(void*)&gsrT, (void*)&bceGI, (void*)&pWeh, (void*)&Wf,
                     (void*)&hb3, (void*)&Afin};
    hipLaunchCooperativeKernel(reinterpret_cast<void*>(edge_lstm),
                               dim3(256), dim3(512), eargs, 0, stream);
  }
  hipLaunchKernelGGL(finalize, dim3(25), dim3(256), 0, stream,
                     Afin, bfp, out);
}